// Round 9
// baseline (389.380 us; speedup 1.0000x reference)
//
#include <hip/hip_runtime.h>
#include <stdint.h>

// Segment layout (elements in each battle row of 10451 floats):
//  player 9 @0 | status 86 @9 | pinfo 8 @95 | 13 x card(740) @103 | potions 43 @9723
//  | relics 180 @9766 | 5 x monster(101) @9946
// Output row (542 floats): player4 @0 | status16 @4 | pinfo2 @20 | cards 13*32 @22
//  | potions8 @438 | relics16 @446 | monsters 5*16 @462
//
// R8 structure (1 battle row per card block, 4 blocks/CU) + LDS +1-float pad
// per card sub-row. The A-fragment read stride was 740 floats (740 mod 32 = 4)
// -> 8-way bank conflict on every ds_read_b128 (8 lanes per 16B window); LDS
// is per-CU shared so extra occupancy couldn't hide it (R8 null). Pad to 741
// (741 mod 32 = 5, gcd(5,32)=1) -> max 2 lanes/window = conflict-free.
// Done legally under global_load_lds (linear dest) by pre-swizzling the
// per-lane GLOBAL source index (incremental s,k decomposition). Reads beyond
// k=740 hit pad/next-sub garbage, killed by zero-padded W. cvt_pk fragments,
// frag-interleaved W, small-segment windowed-LDS path unchanged.

typedef __attribute__((ext_vector_type(8))) short short8;
typedef __attribute__((ext_vector_type(4))) float f32x4;

__device__ inline unsigned short f2bf(float f) {
  union { float f; uint32_t u; } v; v.f = f;
  uint32_t r = v.u + 0x7FFFu + ((v.u >> 16) & 1u);   // round-to-nearest-even
  return (unsigned short)(r >> 16);
}

// packed bf16 pair via the HW converter (RNE), 1 VALU op for 2 elements
__device__ inline uint32_t cvt2(float lo, float hi) {
  uint32_t r;
  asm("v_cvt_pk_bf16_f32 %0, %1, %2" : "=v"(r) : "v"(lo), "v"(hi));
  return r;
}

union bfrag { short8 s; uint32_t u[4]; };

__device__ inline short8 mk_frag(f32x4 lo, f32x4 hi) {
  bfrag f;
  f.u[0] = cvt2(lo[0], lo[1]);
  f.u[1] = cvt2(lo[2], lo[3]);
  f.u[2] = cvt2(hi[0], hi[1]);
  f.u[3] = cvt2(hi[2], hi[3]);
  return f.s;
}

__device__ inline void gload_dw(const float* g, float* lds) {
  __builtin_amdgcn_global_load_lds(
      (const __attribute__((address_space(1))) void*)g,
      (__attribute__((address_space(3))) void*)lds, 4, 0, 0);
}

// Card W -> fragment-interleaved bf16: dword idx = cs*512 + wn*256 + kg*64 + rl*4 + d
// where cs (0..23) covers k = cs*32 + kg*8 + d*2; n = wn*16 + rl. Zero-padded
// beyond k=740. 12288 dwords = 48 KB.
__global__ __launch_bounds__(256) void pack_w(const float* __restrict__ Wc,
                                              uint32_t* __restrict__ wout) {
  int el = blockIdx.x * 256 + threadIdx.x;
  if (el >= 12288) return;
  int d  = el & 3;
  int rl = (el >> 2) & 15;
  int kg = (el >> 6) & 3;
  int wn = (el >> 8) & 1;
  int cs = el >> 9;
  int n  = wn * 16 + rl;
  int k  = cs * 32 + kg * 8 + d * 2;
  float v0 = (k     < 740) ? Wc[n * 740 + k]     : 0.0f;
  float v1 = (k + 1 < 740) ? Wc[n * 740 + k + 1] : 0.0f;
  wout[el] = (uint32_t)f2bf(v0) | ((uint32_t)f2bf(v1) << 16);
}

__global__ __launch_bounds__(256, 4) void seg_gemm(
    const float* __restrict__ battle,
    const float* __restrict__ Wplayer, const float* __restrict__ Wstatus,
    const float* __restrict__ Wpinfo,  const float* __restrict__ Wpotions,
    const float* __restrict__ Wrelics, const float* __restrict__ Wmonster,
    const uint32_t* __restrict__ wpack2,
    float* __restrict__ out, const float* __restrict__ zpage)
{
  // 40960 B: card = padded span[9728] + wred[512]; small = a[4096] + w[1024]
  __shared__ float shm[10240];
  const int bid  = blockIdx.x;
  const int t    = threadIdx.x;
  const int lane = t & 63;
  const int wv   = t >> 6;
  const int rl   = lane & 15;
  const int kg   = lane >> 4;

  if (bid < 32768) {
    // ======================= card path: 1 battle row =======================
    // LDS[s*741 + k] = row[103 + s*740 + k]  (s = card sub, +1-float pad/sub).
    // Dest linear (slot = r*256+t); source index carried incrementally.
    const float* rowp = battle + (uint32_t)bid * 10451u;
    int s = t / 741;              // 0 for t<256, kept general
    int k = t - s * 741;
    #pragma unroll
    for (int r = 0; r < 38; ++r) {
      const int src = 103 + s * 740 + ((k < 740) ? k : 0);  // pad slot: dead data
      gload_dw(rowp + src, &shm[r * 256 + t]);
      k += 256;
      if (k >= 741) { k -= 741; s += 1; }
    }
    __syncthreads();   // drains vmcnt(0); A span read-only afterwards

    const int wn = wv & 1;            // n-half of the 32 outputs
    const int wk = wv >> 1;           // K-half (12 chunks each)
    const uint32_t abase = (rl < 13) ? (uint32_t)(rl * 741) : 0u;  // padded stride
    float* wred = &shm[9728];

    f32x4 acc = {0.f, 0.f, 0.f, 0.f};
    #pragma unroll
    for (int si = 0; si < 12; ++si) {
      const int cs = wk * 12 + si;    // k = cs*32 + kg*8 (+0..7)
      const float* ap = shm + abase + (uint32_t)(cs * 32 + kg * 8);
      f32x4 lo = *(const f32x4*)ap;
      f32x4 hi = *(const f32x4*)(ap + 4);
      short8 aa = mk_frag(lo, hi);
      short8 wf = *(const short8*)(wpack2 + (uint32_t)(cs * 512 + wn * 256 + kg * 64 + rl * 4));
      acc = __builtin_amdgcn_mfma_f32_16x16x32_bf16(aa, wf, acc, 0, 0, 0);
    }

    // reduce K-halves: wk=1 -> wred; barrier; wk=0 adds + stores.
    if (wk == 1) {
      #pragma unroll
      for (int q = 0; q < 4; ++q)
        wred[wn * 256 + (kg * 4 + q) * 16 + rl] = acc[q];
    }
    __syncthreads();
    if (wk == 0) {
      const uint32_t ob = (uint32_t)bid * 542u + 22u;
      #pragma unroll
      for (int q = 0; q < 4; ++q) {
        const int sub = kg * 4 + q;   // C/D: row = kg*4+q (sub), col = rl (n)
        float v = acc[q] + wred[wn * 256 + (kg * 4 + q) * 16 + rl];
        if (sub < 13)
          out[ob + (uint32_t)(sub * 32 + wn * 16 + rl)] = v;
      }
    }
    return;
  }

  // ======================= small-segment path (R1 structure) =======================
  const int sb = bid - 32768;
  int bloc, nsub, K, NOUT, soff, ooff;
  const float* wp;
  if (sb < 1280)      { bloc = sb;        nsub = 5; K = 101; NOUT = 16; soff = 9946; ooff = 462; wp = Wmonster; }
  else if (sb < 1536) { bloc = sb - 1280; nsub = 1; K = 180; NOUT = 16; soff = 9766; ooff = 446; wp = Wrelics; }
  else if (sb < 1792) { bloc = sb - 1536; nsub = 1; K = 86;  NOUT = 16; soff = 9;    ooff = 4;   wp = Wstatus; }
  else if (sb < 2048) { bloc = sb - 1792; nsub = 1; K = 43;  NOUT = 8;  soff = 9723; ooff = 438; wp = Wpotions; }
  else if (sb < 2304) { bloc = sb - 2048; nsub = 1; K = 9;   NOUT = 4;  soff = 0;    ooff = 0;   wp = Wplayer; }
  else                { bloc = sb - 2304; nsub = 1; K = 8;   NOUT = 2;  soff = 95;   ooff = 20;  wp = Wpinfo; }

  float* lds_a = shm;            // [128][32] fp32, 16B-granule XOR-swizzled
  float* lds_w = shm + 4096;     // [32][32]

  const int mb = bloc * 128;
  const int r0 = t >> 5;

  uint32_t rb[16];
  #pragma unroll
  for (int i = 0; i < 16; ++i) {
    uint32_t m   = (uint32_t)(mb + r0 + 8 * i);
    uint32_t b   = m / (uint32_t)nsub;
    uint32_t sub = m - b * (uint32_t)nsub;
    rb[i] = b * 10451u + (uint32_t)soff + sub * (uint32_t)K;
  }

  const int klin = t & 31;
  const int lk   = (((klin >> 2) ^ r0) << 2) | (klin & 3);

  f32x4 acc[2] = {};
  const int nch = (K + 31) >> 5;

  for (int ch = 0; ch < nch; ++ch) {
    const int kk = (ch << 5) + lk;
    #pragma unroll
    for (int i = 0; i < 16; ++i) {
      const float* sp = (kk < K) ? (battle + rb[i] + kk) : zpage;
      gload_dw(sp, &lds_a[i * 256 + t]);
    }
    #pragma unroll
    for (int i = 0; i < 4; ++i) {
      const int col = r0 + 8 * i;
      const float* sp = (col < NOUT && kk < K) ? (wp + col * K + kk) : zpage;
      gload_dw(sp, &lds_w[i * 256 + t]);
    }
    __syncthreads();

    short8 af[2], bfr;
    #pragma unroll
    for (int mf = 0; mf < 2; ++mf) {
      const int rr  = wv * 32 + mf * 16 + rl;
      const int g0i = (2 * kg) ^ (rr & 7);
      const int g1i = (2 * kg + 1) ^ (rr & 7);
      f32x4 lo = *(const f32x4*)&lds_a[rr * 32 + g0i * 4];
      f32x4 hi = *(const f32x4*)&lds_a[rr * 32 + g1i * 4];
      af[mf] = mk_frag(lo, hi);
    }
    {
      const int c   = rl;            // NOUT <= 16 for all small segments
      const int g0i = (2 * kg) ^ (c & 7);
      const int g1i = (2 * kg + 1) ^ (c & 7);
      f32x4 lo = *(const f32x4*)&lds_w[c * 32 + g0i * 4];
      f32x4 hi = *(const f32x4*)&lds_w[c * 32 + g1i * 4];
      bfr = mk_frag(lo, hi);
    }
    #pragma unroll
    for (int mf = 0; mf < 2; ++mf)
      acc[mf] = __builtin_amdgcn_mfma_f32_16x16x32_bf16(af[mf], bfr, acc[mf], 0, 0, 0);

    __syncthreads();
  }

  #pragma unroll
  for (int mf = 0; mf < 2; ++mf) {
    #pragma unroll
    for (int q = 0; q < 4; ++q) {
      uint32_t m   = (uint32_t)(mb + wv * 32 + mf * 16 + kg * 4 + q);
      uint32_t b   = m / (uint32_t)nsub;
      uint32_t sub = m - b * (uint32_t)nsub;
      uint32_t ob  = b * 542u + (uint32_t)ooff + sub * (uint32_t)NOUT;
      const int col = rl;
      if (col < NOUT) out[ob + col] = acc[mf][q];
    }
  }
}

extern "C" void kernel_launch(void* const* d_in, const int* in_sizes, int n_in,
                              void* d_out, int out_size, void* d_ws, size_t ws_size,
                              hipStream_t stream) {
  const float* battle   = (const float*)d_in[0];
  const float* Wplayer  = (const float*)d_in[1];
  const float* Wstatus  = (const float*)d_in[2];
  const float* Wpinfo   = (const float*)d_in[3];
  const float* Wcard    = (const float*)d_in[4];
  const float* Wpotions = (const float*)d_in[5];
  const float* Wrelics  = (const float*)d_in[6];
  const float* Wmonster = (const float*)d_in[7];
  float* out = (float*)d_out;

  // ws layout: [0,256) zero page | [256, 256+49152) frag-interleaved card W
  const float* zpage = (const float*)d_ws;
  uint32_t* wpack2 = (uint32_t*)((char*)d_ws + 256);

  hipMemsetAsync(d_ws, 0, 256, stream);
  hipLaunchKernelGGL(pack_w, dim3(48), dim3(256), 0, stream, Wcard, wpack2);
  hipLaunchKernelGGL(seg_gemm, dim3(35328), dim3(256), 0, stream,
                     battle, Wplayer, Wstatus, Wpinfo, Wpotions, Wrelics,
                     Wmonster, (const uint32_t*)wpack2, out, zpage);
}

// Round 12
// 387.488 us; speedup vs baseline: 1.0049x; 1.0049x over previous
//
#include <hip/hip_runtime.h>
#include <stdint.h>

// Segment layout (elements in each battle row of 10451 floats):
//  player 9 @0 | status 86 @9 | pinfo 8 @95 | 13 x card(740) @103 | potions 43 @9723
//  | relics 180 @9766 | 5 x monster(101) @9946
// Output row (542 floats): player4 @0 | status16 @4 | pinfo2 @20 | cards 13*32 @22
//  | potions8 @438 | relics16 @446 | monsters 5*16 @462
//
// R8 structure (1 battle row per card block, 4 blocks/CU, cvt_pk fragments,
// frag-interleaved bf16 W) with two changes:
//  1. Card staging via WIDTH-16 global_load_lds (m193: width 4->16 = +67% on
//     GEMM staging). 10 DMA instr/block instead of 38. The 4B-only alignment
//     of the card span is handled by staging from the 16B-aligned base and
//     adding the uniform shift delta (0..3 floats) to fragment reads.
//     In-bounds proof: staged window [row_el, base4+9728) sits inside
//     [b*10451+103, b*10451+9831) -- always within row b's 10451 floats.
//  2. Small-segment blocks FIRST in the grid so they overlap the card stream
//     instead of forming a serialized tail.
// R9 lesson: stride-740 b128 LDS reads phase conflict-free; no padding.

typedef __attribute__((ext_vector_type(8))) short short8;
typedef __attribute__((ext_vector_type(4))) float f32x4;

__device__ inline unsigned short f2bf(float f) {
  union { float f; uint32_t u; } v; v.f = f;
  uint32_t r = v.u + 0x7FFFu + ((v.u >> 16) & 1u);   // round-to-nearest-even
  return (unsigned short)(r >> 16);
}

// packed bf16 pair via the HW converter (RNE), 1 VALU op for 2 elements
__device__ inline uint32_t cvt2(float lo, float hi) {
  uint32_t r;
  asm("v_cvt_pk_bf16_f32 %0, %1, %2" : "=v"(r) : "v"(lo), "v"(hi));
  return r;
}

union bfrag { short8 s; uint32_t u[4]; };

__device__ inline short8 mk_frag(f32x4 lo, f32x4 hi) {
  bfrag f;
  f.u[0] = cvt2(lo[0], lo[1]);
  f.u[1] = cvt2(lo[2], lo[3]);
  f.u[2] = cvt2(hi[0], hi[1]);
  f.u[3] = cvt2(hi[2], hi[3]);
  return f.s;
}

__device__ inline void gload_dw(const float* g, float* lds) {
  __builtin_amdgcn_global_load_lds(
      (const __attribute__((address_space(1))) void*)g,
      (__attribute__((address_space(3))) void*)lds, 4, 0, 0);
}

__device__ inline void gload16(const float* g, float* lds) {
  __builtin_amdgcn_global_load_lds(
      (const __attribute__((address_space(1))) void*)g,
      (__attribute__((address_space(3))) void*)lds, 16, 0, 0);
}

// Card W -> fragment-interleaved bf16: dword idx = cs*512 + wn*256 + kg*64 + rl*4 + d
// where cs (0..23) covers k = cs*32 + kg*8 + d*2; n = wn*16 + rl. Zero-padded
// beyond k=740. 12288 dwords = 48 KB.
__global__ __launch_bounds__(256) void pack_w(const float* __restrict__ Wc,
                                              uint32_t* __restrict__ wout) {
  int el = blockIdx.x * 256 + threadIdx.x;
  if (el >= 12288) return;
  int d  = el & 3;
  int rl = (el >> 2) & 15;
  int kg = (el >> 6) & 3;
  int wn = (el >> 8) & 1;
  int cs = el >> 9;
  int n  = wn * 16 + rl;
  int k  = cs * 32 + kg * 8 + d * 2;
  float v0 = (k     < 740) ? Wc[n * 740 + k]     : 0.0f;
  float v1 = (k + 1 < 740) ? Wc[n * 740 + k + 1] : 0.0f;
  wout[el] = (uint32_t)f2bf(v0) | ((uint32_t)f2bf(v1) << 16);
}

__global__ __launch_bounds__(256, 4) void seg_gemm(
    const float* __restrict__ battle,
    const float* __restrict__ Wplayer, const float* __restrict__ Wstatus,
    const float* __restrict__ Wpinfo,  const float* __restrict__ Wpotions,
    const float* __restrict__ Wrelics, const float* __restrict__ Wmonster,
    const uint32_t* __restrict__ wpack2,
    float* __restrict__ out, const float* __restrict__ zpage)
{
  // 40960 B: card = span[9728] + wred[512]; small = a[4096] + w[1024] (union)
  __shared__ float shm[10240];
  const int bid  = blockIdx.x;
  const int t    = threadIdx.x;
  const int lane = t & 63;
  const int wv   = t >> 6;
  const int rl   = lane & 15;
  const int kg   = lane >> 4;

  if (bid >= 2560) {
    // ======================= card path: 1 battle row =======================
    const int cb = bid - 2560;                 // 0..32767
    const uint32_t row_el = (uint32_t)cb * 10451u + 103u;
    const uint32_t base4  = row_el & ~3u;      // 16B-aligned staging base
    const uint32_t delta  = row_el - base4;    // 0..3, wave-uniform

    // stage 9728 floats [base4, base4+9728) via width-16 DMA: 9 full rounds
    // (1KB/wave-instr) + 1 half-block round. Dest linear = wave base + lane*16.
    #pragma unroll
    for (int r = 0; r < 9; ++r)
      gload16(battle + base4 + (uint32_t)(r * 1024 + t * 4), &shm[r * 1024 + t * 4]);
    if (t < 128)
      gload16(battle + base4 + (uint32_t)(9216 + t * 4), &shm[9216 + t * 4]);
    __syncthreads();   // drains vmcnt(0); A span read-only afterwards

    const int wn = wv & 1;            // n-half of the 32 outputs
    const int wk = wv >> 1;           // K-half (12 chunks each)
    const uint32_t abase = delta + ((rl < 13) ? (uint32_t)(rl * 740) : 0u);
    float* wred = &shm[9728];

    f32x4 acc = {0.f, 0.f, 0.f, 0.f};
    #pragma unroll
    for (int si = 0; si < 12; ++si) {
      const int cs = wk * 12 + si;    // k = cs*32 + kg*8 (+0..7)
      const float* ap = shm + abase + (uint32_t)(cs * 32 + kg * 8);
      f32x4 lo = *(const f32x4*)ap;
      f32x4 hi = *(const f32x4*)(ap + 4);
      short8 aa = mk_frag(lo, hi);
      short8 wf = *(const short8*)(wpack2 + (uint32_t)(cs * 512 + wn * 256 + kg * 64 + rl * 4));
      acc = __builtin_amdgcn_mfma_f32_16x16x32_bf16(aa, wf, acc, 0, 0, 0);
    }

    // reduce K-halves: wk=1 -> wred; barrier; wk=0 adds + stores.
    if (wk == 1) {
      #pragma unroll
      for (int q = 0; q < 4; ++q)
        wred[wn * 256 + (kg * 4 + q) * 16 + rl] = acc[q];
    }
    __syncthreads();
    if (wk == 0) {
      const uint32_t ob = (uint32_t)cb * 542u + 22u;
      #pragma unroll
      for (int q = 0; q < 4; ++q) {
        const int sub = kg * 4 + q;   // C/D: row = kg*4+q (sub), col = rl (n)
        float v = acc[q] + wred[wn * 256 + (kg * 4 + q) * 16 + rl];
        if (sub < 13)
          out[ob + (uint32_t)(sub * 32 + wn * 16 + rl)] = v;
      }
    }
    return;
  }

  // ======================= small-segment path (R1 structure) =======================
  const int sb = bid;                          // 0..2559, runs FIRST in the grid
  int bloc, nsub, K, NOUT, soff, ooff;
  const float* wp;
  if (sb < 1280)      { bloc = sb;        nsub = 5; K = 101; NOUT = 16; soff = 9946; ooff = 462; wp = Wmonster; }
  else if (sb < 1536) { bloc = sb - 1280; nsub = 1; K = 180; NOUT = 16; soff = 9766; ooff = 446; wp = Wrelics; }
  else if (sb < 1792) { bloc = sb - 1536; nsub = 1; K = 86;  NOUT = 16; soff = 9;    ooff = 4;   wp = Wstatus; }
  else if (sb < 2048) { bloc = sb - 1792; nsub = 1; K = 43;  NOUT = 8;  soff = 9723; ooff = 438; wp = Wpotions; }
  else if (sb < 2304) { bloc = sb - 2048; nsub = 1; K = 9;   NOUT = 4;  soff = 0;    ooff = 0;   wp = Wplayer; }
  else                { bloc = sb - 2304; nsub = 1; K = 8;   NOUT = 2;  soff = 95;   ooff = 20;  wp = Wpinfo; }

  float* lds_a = shm;            // [128][32] fp32, 16B-granule XOR-swizzled
  float* lds_w = shm + 4096;     // [32][32]

  const int mb = bloc * 128;
  const int r0 = t >> 5;

  uint32_t rb[16];
  #pragma unroll
  for (int i = 0; i < 16; ++i) {
    uint32_t m   = (uint32_t)(mb + r0 + 8 * i);
    uint32_t b   = m / (uint32_t)nsub;
    uint32_t sub = m - b * (uint32_t)nsub;
    rb[i] = b * 10451u + (uint32_t)soff + sub * (uint32_t)K;
  }

  const int klin = t & 31;
  const int lk   = (((klin >> 2) ^ r0) << 2) | (klin & 3);

  f32x4 acc[2] = {};
  const int nch = (K + 31) >> 5;

  for (int ch = 0; ch < nch; ++ch) {
    const int kk = (ch << 5) + lk;
    #pragma unroll
    for (int i = 0; i < 16; ++i) {
      const float* sp = (kk < K) ? (battle + rb[i] + kk) : zpage;
      gload_dw(sp, &lds_a[i * 256 + t]);
    }
    #pragma unroll
    for (int i = 0; i < 4; ++i) {
      const int col = r0 + 8 * i;
      const float* sp = (col < NOUT && kk < K) ? (wp + col * K + kk) : zpage;
      gload_dw(sp, &lds_w[i * 256 + t]);
    }
    __syncthreads();

    short8 af[2], bfr;
    #pragma unroll
    for (int mf = 0; mf < 2; ++mf) {
      const int rr  = wv * 32 + mf * 16 + rl;
      const int g0i = (2 * kg) ^ (rr & 7);
      const int g1i = (2 * kg + 1) ^ (rr & 7);
      f32x4 lo = *(const f32x4*)&lds_a[rr * 32 + g0i * 4];
      f32x4 hi = *(const f32x4*)&lds_a[rr * 32 + g1i * 4];
      af[mf] = mk_frag(lo, hi);
    }
    {
      const int c   = rl;            // NOUT <= 16 for all small segments
      const int g0i = (2 * kg) ^ (c & 7);
      const int g1i = (2 * kg + 1) ^ (c & 7);
      f32x4 lo = *(const f32x4*)&lds_w[c * 32 + g0i * 4];
      f32x4 hi = *(const f32x4*)&lds_w[c * 32 + g1i * 4];
      bfr = mk_frag(lo, hi);
    }
    #pragma unroll
    for (int mf = 0; mf < 2; ++mf)
      acc[mf] = __builtin_amdgcn_mfma_f32_16x16x32_bf16(af[mf], bfr, acc[mf], 0, 0, 0);

    __syncthreads();
  }

  #pragma unroll
  for (int mf = 0; mf < 2; ++mf) {
    #pragma unroll
    for (int q = 0; q < 4; ++q) {
      uint32_t m   = (uint32_t)(mb + wv * 32 + mf * 16 + kg * 4 + q);
      uint32_t b   = m / (uint32_t)nsub;
      uint32_t sub = m - b * (uint32_t)nsub;
      uint32_t ob  = b * 542u + (uint32_t)ooff + sub * (uint32_t)NOUT;
      const int col = rl;
      if (col < NOUT) out[ob + col] = acc[mf][q];
    }
  }
}

extern "C" void kernel_launch(void* const* d_in, const int* in_sizes, int n_in,
                              void* d_out, int out_size, void* d_ws, size_t ws_size,
                              hipStream_t stream) {
  const float* battle   = (const float*)d_in[0];
  const float* Wplayer  = (const float*)d_in[1];
  const float* Wstatus  = (const float*)d_in[2];
  const float* Wpinfo   = (const float*)d_in[3];
  const float* Wcard    = (const float*)d_in[4];
  const float* Wpotions = (const float*)d_in[5];
  const float* Wrelics  = (const float*)d_in[6];
  const float* Wmonster = (const float*)d_in[7];
  float* out = (float*)d_out;

  // ws layout: [0,256) zero page | [256, 256+49152) frag-interleaved card W
  const float* zpage = (const float*)d_ws;
  uint32_t* wpack2 = (uint32_t*)((char*)d_ws + 256);

  hipMemsetAsync(d_ws, 0, 256, stream);
  hipLaunchKernelGGL(pack_w, dim3(48), dim3(256), 0, stream, Wcard, wpack2);
  hipLaunchKernelGGL(seg_gemm, dim3(35328), dim3(256), 0, stream,
                     battle, Wplayer, Wstatus, Wpinfo, Wpotions, Wrelics,
                     Wmonster, (const uint32_t*)wpack2, out, zpage);
}

// Round 13
// 305.593 us; speedup vs baseline: 1.2742x; 1.2680x over previous
//
#include <hip/hip_runtime.h>
#include <stdint.h>

// Segment layout (elements in each battle row of 10451 floats):
//  player 9 @0 | status 86 @9 | pinfo 8 @95 | 13 x card(740) @103 | potions 43 @9723
//  | relics 180 @9766 | 5 x monster(101) @9946
// Output row (542 floats): player4 @0 | status16 @4 | pinfo2 @20 | cards 13*32 @22
//  | potions8 @438 | relics16 @446 | monsters 5*16 @462
//
// Card path (T14 reg-staged pipeline): 8 rows/block, LDS double-buffer.
// W fragments are row-invariant -> hoisted to VGPRs at block start, so the
// row loop's ONLY vmem is the A stage (10 dwordx4/thread). Per row: issue
// next row's loads -> compute current row from LDS (no vmem deps; loads
// stream underneath) -> compiler vmcnt wait + ds_write next buffer ->
// barrier. HBM stays fed through the compute phase (the 24% idle that
// global_load_lds could not overlap because hipcc drains vmcnt(0) at the
// barrier: R3/R6/R12). Small segments: R7 windowed-LDS path, at grid end.

typedef __attribute__((ext_vector_type(8))) short short8;
typedef __attribute__((ext_vector_type(4))) float f32x4;
typedef __attribute__((ext_vector_type(4), aligned(4))) float f32x4u;

__device__ inline unsigned short f2bf(float f) {
  union { float f; uint32_t u; } v; v.f = f;
  uint32_t r = v.u + 0x7FFFu + ((v.u >> 16) & 1u);   // round-to-nearest-even
  return (unsigned short)(r >> 16);
}

// packed bf16 pair via the HW converter (RNE), 1 VALU op for 2 elements
__device__ inline uint32_t cvt2(float lo, float hi) {
  uint32_t r;
  asm("v_cvt_pk_bf16_f32 %0, %1, %2" : "=v"(r) : "v"(lo), "v"(hi));
  return r;
}

union bfrag { short8 s; uint32_t u[4]; };

__device__ inline short8 mk_frag(f32x4 lo, f32x4 hi) {
  bfrag f;
  f.u[0] = cvt2(lo[0], lo[1]);
  f.u[1] = cvt2(lo[2], lo[3]);
  f.u[2] = cvt2(hi[0], hi[1]);
  f.u[3] = cvt2(hi[2], hi[3]);
  return f.s;
}

__device__ inline void gload_dw(const float* g, float* lds) {
  __builtin_amdgcn_global_load_lds(
      (const __attribute__((address_space(1))) void*)g,
      (__attribute__((address_space(3))) void*)lds, 4, 0, 0);
}

// Card W -> fragment-interleaved bf16: dword idx = cs*512 + wn*256 + kg*64 + rl*4 + d
// where cs (0..23) covers k = cs*32 + kg*8 + d*2; n = wn*16 + rl. Zero-padded
// beyond k=740. 12288 dwords = 48 KB.
__global__ __launch_bounds__(256) void pack_w(const float* __restrict__ Wc,
                                              uint32_t* __restrict__ wout) {
  int el = blockIdx.x * 256 + threadIdx.x;
  if (el >= 12288) return;
  int d  = el & 3;
  int rl = (el >> 2) & 15;
  int kg = (el >> 6) & 3;
  int wn = (el >> 8) & 1;
  int cs = el >> 9;
  int n  = wn * 16 + rl;
  int k  = cs * 32 + kg * 8 + d * 2;
  float v0 = (k     < 740) ? Wc[n * 740 + k]     : 0.0f;
  float v1 = (k + 1 < 740) ? Wc[n * 740 + k + 1] : 0.0f;
  wout[el] = (uint32_t)f2bf(v0) | ((uint32_t)f2bf(v1) << 16);
}

__global__ __launch_bounds__(256, 2) void seg_gemm(
    const float* __restrict__ battle,
    const float* __restrict__ Wplayer, const float* __restrict__ Wstatus,
    const float* __restrict__ Wpinfo,  const float* __restrict__ Wpotions,
    const float* __restrict__ Wrelics, const float* __restrict__ Wmonster,
    const uint32_t* __restrict__ wpack2,
    float* __restrict__ out, const float* __restrict__ zpage)
{
  // 79872 B: card = dbuf 2x9728 + wred 512; small = a 4096 + w 1024 (union)
  __shared__ float shm[19968];
  const int bid  = blockIdx.x;
  const int t    = threadIdx.x;
  const int lane = t & 63;
  const int wv   = t >> 6;
  const int rl   = lane & 15;
  const int kg   = lane >> 4;

  if (bid < 4096) {
    // ======================= card path: 8 rows, reg-staged =======================
    const int row0 = bid * 8;
    const int wn = wv & 1;            // n-half of the 32 outputs
    const int wk = wv >> 1;           // K-half (12 chunks each)
    float* wred = &shm[19456];

    // hoist W fragments (row-invariant): 12 x short8 = 24 VGPR
    short8 wfr[12];
    #pragma unroll
    for (int si = 0; si < 12; ++si) {
      const int cs = wk * 12 + si;
      wfr[si] = *(const short8*)(wpack2 + (uint32_t)(cs * 512 + wn * 256 + kg * 64 + rl * 4));
    }

    f32x4 sreg[10];                   // staged A row: 38 floats + pad, 40 VGPR
    #define LOADR(r_) do {                                                      \
      const uint32_t row_el_ = (uint32_t)(row0 + (r_)) * 10451u + 103u;         \
      const uint32_t b4_ = row_el_ & ~3u;                                       \
      _Pragma("unroll")                                                         \
      for (int rr = 0; rr < 9; ++rr)                                            \
        sreg[rr] = *(const f32x4u*)(battle + b4_ + (uint32_t)(rr * 1024 + t * 4)); \
      if (t < 128)                                                              \
        sreg[9] = *(const f32x4u*)(battle + b4_ + (uint32_t)(9216 + t * 4));    \
    } while (0)
    #define WRITEB(buf_) do {                                                   \
      _Pragma("unroll")                                                         \
      for (int rr = 0; rr < 9; ++rr)                                            \
        *(f32x4*)&(buf_)[rr * 1024 + t * 4] = sreg[rr];                         \
      if (t < 128)                                                              \
        *(f32x4*)&(buf_)[9216 + t * 4] = sreg[9];                               \
    } while (0)

    LOADR(0);
    WRITEB(&shm[0]);
    __syncthreads();

    for (int r = 0; r < 8; ++r) {
      const int cur = r & 1;
      if (r + 1 < 8) LOADR(r + 1);    // issue next row's loads EARLY

      // ---- compute row r from buf[cur]: zero vmem deps, loads stream ----
      const uint32_t row_el = (uint32_t)(row0 + r) * 10451u + 103u;
      const uint32_t delta  = row_el & 3u;       // staged from base4 = row_el-delta
      const float* abuf = &shm[cur * 9728];
      const uint32_t abase = delta + ((rl < 13) ? (uint32_t)(rl * 740) : 0u);

      f32x4 acc = {0.f, 0.f, 0.f, 0.f};
      #pragma unroll
      for (int si = 0; si < 12; ++si) {
        const int cs = wk * 12 + si;             // k = cs*32 + kg*8 (+0..7)
        const float* ap = abuf + abase + (uint32_t)(cs * 32 + kg * 8);
        f32x4 lo = *(const f32x4u*)ap;           // 4B-aligned LDS reads (delta)
        f32x4 hi = *(const f32x4u*)(ap + 4);
        short8 aa = mk_frag(lo, hi);
        acc = __builtin_amdgcn_mfma_f32_16x16x32_bf16(aa, wfr[si], acc, 0, 0, 0);
      }

      // reduce K-halves: wk=1 -> wred; barrier; wk=0 adds + stores.
      if (wk == 1) {
        #pragma unroll
        for (int q = 0; q < 4; ++q)
          wred[wn * 256 + (kg * 4 + q) * 16 + rl] = acc[q];
      }
      __syncthreads();
      if (wk == 0) {
        const uint32_t ob = (uint32_t)(row0 + r) * 542u + 22u;
        #pragma unroll
        for (int q = 0; q < 4; ++q) {
          const int sub = kg * 4 + q;   // C/D: row = kg*4+q (sub), col = rl (n)
          float v = acc[q] + wred[wn * 256 + (kg * 4 + q) * 16 + rl];
          if (sub < 13)
            out[ob + (uint32_t)(sub * 32 + wn * 16 + rl)] = v;
        }
      }

      // ---- write next row into the other buffer (vmcnt waits land here) ----
      if (r + 1 < 8) WRITEB(&shm[(cur ^ 1) * 9728]);
      __syncthreads();   // buf ready for next iter; orders wred reuse
    }
    return;
  }

  // ======================= small-segment path (R7 structure) =======================
  const int sb = bid - 4096;                     // 0..2559
  int bloc, nsub, K, NOUT, soff, ooff;
  const float* wp;
  if (sb < 1280)      { bloc = sb;        nsub = 5; K = 101; NOUT = 16; soff = 9946; ooff = 462; wp = Wmonster; }
  else if (sb < 1536) { bloc = sb - 1280; nsub = 1; K = 180; NOUT = 16; soff = 9766; ooff = 446; wp = Wrelics; }
  else if (sb < 1792) { bloc = sb - 1536; nsub = 1; K = 86;  NOUT = 16; soff = 9;    ooff = 4;   wp = Wstatus; }
  else if (sb < 2048) { bloc = sb - 1792; nsub = 1; K = 43;  NOUT = 8;  soff = 9723; ooff = 438; wp = Wpotions; }
  else if (sb < 2304) { bloc = sb - 2048; nsub = 1; K = 9;   NOUT = 4;  soff = 0;    ooff = 0;   wp = Wplayer; }
  else                { bloc = sb - 2304; nsub = 1; K = 8;   NOUT = 2;  soff = 95;   ooff = 20;  wp = Wpinfo; }

  float* lds_a = shm;            // [128][32] fp32, 16B-granule XOR-swizzled
  float* lds_w = shm + 4096;     // [32][32]

  const int mb = bloc * 128;
  const int r0 = t >> 5;

  uint32_t rb[16];
  #pragma unroll
  for (int i = 0; i < 16; ++i) {
    uint32_t m   = (uint32_t)(mb + r0 + 8 * i);
    uint32_t b   = m / (uint32_t)nsub;
    uint32_t sub = m - b * (uint32_t)nsub;
    rb[i] = b * 10451u + (uint32_t)soff + sub * (uint32_t)K;
  }

  const int klin = t & 31;
  const int lk   = (((klin >> 2) ^ r0) << 2) | (klin & 3);

  f32x4 acc[2] = {};
  const int nch = (K + 31) >> 5;

  for (int ch = 0; ch < nch; ++ch) {
    const int kk = (ch << 5) + lk;
    #pragma unroll
    for (int i = 0; i < 16; ++i) {
      const float* sp = (kk < K) ? (battle + rb[i] + kk) : zpage;
      gload_dw(sp, &lds_a[i * 256 + t]);
    }
    #pragma unroll
    for (int i = 0; i < 4; ++i) {
      const int col = r0 + 8 * i;
      const float* sp = (col < NOUT && kk < K) ? (wp + col * K + kk) : zpage;
      gload_dw(sp, &lds_w[i * 256 + t]);
    }
    __syncthreads();

    short8 af[2], bfr;
    #pragma unroll
    for (int mf = 0; mf < 2; ++mf) {
      const int rr  = wv * 32 + mf * 16 + rl;
      const int g0i = (2 * kg) ^ (rr & 7);
      const int g1i = (2 * kg + 1) ^ (rr & 7);
      f32x4 lo = *(const f32x4*)&lds_a[rr * 32 + g0i * 4];
      f32x4 hi = *(const f32x4*)&lds_a[rr * 32 + g1i * 4];
      af[mf] = mk_frag(lo, hi);
    }
    {
      const int c   = rl;            // NOUT <= 16 for all small segments
      const int g0i = (2 * kg) ^ (c & 7);
      const int g1i = (2 * kg + 1) ^ (c & 7);
      f32x4 lo = *(const f32x4*)&lds_w[c * 32 + g0i * 4];
      f32x4 hi = *(const f32x4*)&lds_w[c * 32 + g1i * 4];
      bfr = mk_frag(lo, hi);
    }
    #pragma unroll
    for (int mf = 0; mf < 2; ++mf)
      acc[mf] = __builtin_amdgcn_mfma_f32_16x16x32_bf16(af[mf], bfr, acc[mf], 0, 0, 0);

    __syncthreads();
  }

  #pragma unroll
  for (int mf = 0; mf < 2; ++mf) {
    #pragma unroll
    for (int q = 0; q < 4; ++q) {
      uint32_t m   = (uint32_t)(mb + wv * 32 + mf * 16 + kg * 4 + q);
      uint32_t b   = m / (uint32_t)nsub;
      uint32_t sub = m - b * (uint32_t)nsub;
      uint32_t ob  = b * 542u + (uint32_t)ooff + sub * (uint32_t)NOUT;
      const int col = rl;
      if (col < NOUT) out[ob + col] = acc[mf][q];
    }
  }
}

extern "C" void kernel_launch(void* const* d_in, const int* in_sizes, int n_in,
                              void* d_out, int out_size, void* d_ws, size_t ws_size,
                              hipStream_t stream) {
  const float* battle   = (const float*)d_in[0];
  const float* Wplayer  = (const float*)d_in[1];
  const float* Wstatus  = (const float*)d_in[2];
  const float* Wpinfo   = (const float*)d_in[3];
  const float* Wcard    = (const float*)d_in[4];
  const float* Wpotions = (const float*)d_in[5];
  const float* Wrelics  = (const float*)d_in[6];
  const float* Wmonster = (const float*)d_in[7];
  float* out = (float*)d_out;

  // ws layout: [0,256) zero page | [256, 256+49152) frag-interleaved card W
  const float* zpage = (const float*)d_ws;
  uint32_t* wpack2 = (uint32_t*)((char*)d_ws + 256);

  hipMemsetAsync(d_ws, 0, 256, stream);
  hipLaunchKernelGGL(pack_w, dim3(48), dim3(256), 0, stream, Wcard, wpack2);
  hipLaunchKernelGGL(seg_gemm, dim3(6656), dim3(256), 0, stream,
                     battle, Wplayer, Wstatus, Wpinfo, Wpotions, Wrelics,
                     Wmonster, (const uint32_t*)wpack2, out, zpage);
}

// Round 14
// 301.915 us; speedup vs baseline: 1.2897x; 1.0122x over previous
//
#include <hip/hip_runtime.h>
#include <stdint.h>

// Segment layout (elements in each battle row of 10451 floats):
//  player 9 @0 | status 86 @9 | pinfo 8 @95 | 13 x card(740) @103 | potions 43 @9723
//  | relics 180 @9766 | 5 x monster(101) @9946
// Output row (542 floats): player4 @0 | status16 @4 | pinfo2 @20 | cards 13*32 @22
//  | potions8 @438 | relics16 @446 | monsters 5*16 @462
//
// UNIFIED one-row blocks (32768): card path identical to the proven R8
// structure (38 width-4 global_load_lds rounds, 4 waves = n-half x K-half,
// cvt_pk fragments, wred reduce). Added: an 880-float small-segment LDS area
// staged via per-lane-source DMA (4 rounds), and the small segments computed
// as extra MFMA chunks on waves 0-2 (M=1 / M=5 tiles; k-tails hit zero-padded
// W; all garbage A is finite battle data so x0 == 0). Removes the 2560
// small-segment blocks, their 1.5x windowed overfetch (~55 MB), the zero
// page, and the memset launch. W: ALL segments packed frag-interleaved (41
// chunks x 512 dwords). LDS 44480 B -> 3 blocks/CU.

typedef __attribute__((ext_vector_type(8))) short short8;
typedef __attribute__((ext_vector_type(4))) float f32x4;

__device__ inline unsigned short f2bf(float f) {
  union { float f; uint32_t u; } v; v.f = f;
  uint32_t r = v.u + 0x7FFFu + ((v.u >> 16) & 1u);   // round-to-nearest-even
  return (unsigned short)(r >> 16);
}

// packed bf16 pair via the HW converter (RNE), 1 VALU op for 2 elements
__device__ inline uint32_t cvt2(float lo, float hi) {
  uint32_t r;
  asm("v_cvt_pk_bf16_f32 %0, %1, %2" : "=v"(r) : "v"(lo), "v"(hi));
  return r;
}

union bfrag { short8 s; uint32_t u[4]; };

__device__ inline short8 mk_frag(f32x4 lo, f32x4 hi) {
  bfrag f;
  f.u[0] = cvt2(lo[0], lo[1]);
  f.u[1] = cvt2(lo[2], lo[3]);
  f.u[2] = cvt2(hi[0], hi[1]);
  f.u[3] = cvt2(hi[2], hi[3]);
  return f.s;
}

__device__ inline void gload_dw(const float* g, float* lds) {
  __builtin_amdgcn_global_load_lds(
      (const __attribute__((address_space(1))) void*)g,
      (__attribute__((address_space(3))) void*)lds, 4, 0, 0);
}

// W -> fragment-interleaved bf16. 41 chunks x 512 dwords:
//  chunk 0..23 card | 24..26 status | 27..28 potions | 29 player | 30 pinfo
//  | 31..34 monster | 35..40 relics.
// dword idx = chunk*512 + wn*256 + kg*64 + rl*4 + d holds W[n][k],W[n][k+1]
// with n = wn*16+rl, k = (chunk-cbase)*32 + kg*8 + d*2; zero outside NOUT/K.
__global__ __launch_bounds__(256) void pack_w(
    const float* __restrict__ Wp, const float* __restrict__ Ws,
    const float* __restrict__ Wpi, const float* __restrict__ Wc,
    const float* __restrict__ Wpo, const float* __restrict__ Wr,
    const float* __restrict__ Wm, uint32_t* __restrict__ wout) {
  int el = blockIdx.x * 256 + threadIdx.x;
  if (el >= 20992) return;
  int d  = el & 3;
  int rl = (el >> 2) & 15;
  int kg = (el >> 6) & 3;
  int wn = (el >> 8) & 1;
  int chunk = el >> 9;
  const float* w; int K, NOUT, cbase;
  if (chunk < 24)      { w = Wc;  K = 740; NOUT = 32; cbase = 0; }
  else if (chunk < 27) { w = Ws;  K = 86;  NOUT = 16; cbase = 24; }
  else if (chunk < 29) { w = Wpo; K = 43;  NOUT = 8;  cbase = 27; }
  else if (chunk < 30) { w = Wp;  K = 9;   NOUT = 4;  cbase = 29; }
  else if (chunk < 31) { w = Wpi; K = 8;   NOUT = 2;  cbase = 30; }
  else if (chunk < 35) { w = Wm;  K = 101; NOUT = 16; cbase = 31; }
  else                 { w = Wr;  K = 180; NOUT = 16; cbase = 35; }
  int n = wn * 16 + rl;
  int k = (chunk - cbase) * 32 + kg * 8 + d * 2;
  float v0 = (n < NOUT && k     < K) ? w[n * K + k]     : 0.0f;
  float v1 = (n < NOUT && k + 1 < K) ? w[n * K + k + 1] : 0.0f;
  wout[el] = (uint32_t)f2bf(v0) | ((uint32_t)f2bf(v1) << 16);
}

__global__ __launch_bounds__(256, 3) void seg_gemm(
    const float* __restrict__ battle,
    const uint32_t* __restrict__ wpack2,
    float* __restrict__ out)
{
  // LDS: card[0..9728) | smalls[9728..10608) (880) | wred[10608..11120)
  __shared__ float shm[11120];
  const int b    = blockIdx.x;          // battle row
  const int t    = threadIdx.x;
  const int lane = t & 63;
  const int wv   = t >> 6;
  const int rl   = lane & 15;
  const int kg   = lane >> 4;
  const int wn   = wv & 1;              // card n-half
  const int wk   = wv >> 1;             // card K-half

  const uint32_t row = (uint32_t)b * 10451u;

  // ---- stage card region [103, 9831) -> shm[0..9728) (proven R8 path) ----
  #pragma unroll
  for (int r = 0; r < 38; ++r)
    gload_dw(battle + row + 103u + (uint32_t)(r * 256 + t), &shm[r * 256 + t]);

  // ---- stage smalls -> shm[9728..10608): per-lane source map, linear dest --
  // layout (offsets in small area): player@0(9) status@12(86) pinfo@100(8)
  // potions@112(43) relics@156(180) monster@336(5 x stride 104)
  #pragma unroll
  for (int r = 0; r < 4; ++r) {
    const int s = r * 256 + t;
    if (s < 880) {
      int src;
      if (s < 12)        src = s;                 // player (+gap: garbage x0)
      else if (s < 100)  src = 9 + (s - 12);      // status (+tail x0)
      else if (s < 112)  src = 95 + (s - 100);    // pinfo
      else if (s < 156)  src = 9723 + (s - 112);  // potions
      else if (s < 336)  src = 9766 + (s - 156);  // relics
      else if (s < 856) {                         // monster, rows padded to 104
        int sub = (s - 336) / 104;
        int kk  = (s - 336) - sub * 104;
        src = 9946 + sub * 101 + ((kk > 100) ? 100 : kk);
      } else src = 0;                             // pad (finite x0)
      gload_dw(battle + row + (uint32_t)src, &shm[9728 + s]);
    }
  }
  __syncthreads();   // drains vmcnt(0); LDS read-only afterwards

  // ======================= card compute (identical to R8) =======================
  const uint32_t abase = (rl < 13) ? (uint32_t)(rl * 740) : 0u;
  float* wred = &shm[10608];

  f32x4 acc = {0.f, 0.f, 0.f, 0.f};
  #pragma unroll
  for (int si = 0; si < 12; ++si) {
    const int cs = wk * 12 + si;        // k = cs*32 + kg*8 (+0..7)
    const float* ap = shm + abase + (uint32_t)(cs * 32 + kg * 8);
    f32x4 lo = *(const f32x4*)ap;
    f32x4 hi = *(const f32x4*)(ap + 4);
    short8 aa = mk_frag(lo, hi);
    short8 wf = *(const short8*)(wpack2 + (uint32_t)(cs * 512 + wn * 256 + kg * 64 + rl * 4));
    acc = __builtin_amdgcn_mfma_f32_16x16x32_bf16(aa, wf, acc, 0, 0, 0);
  }

  if (wk == 1) {
    #pragma unroll
    for (int q = 0; q < 4; ++q)
      wred[wn * 256 + (kg * 4 + q) * 16 + rl] = acc[q];
  }
  __syncthreads();

  const uint32_t ob0 = (uint32_t)b * 542u;
  if (wk == 0) {
    #pragma unroll
    for (int q = 0; q < 4; ++q) {
      const int sub = kg * 4 + q;       // C/D: row = kg*4+q, col = rl
      float v = acc[q] + wred[wn * 256 + (kg * 4 + q) * 16 + rl];
      if (sub < 13)
        out[ob0 + 22u + (uint32_t)(sub * 32 + wn * 16 + rl)] = v;
    }
  }

  // ======================= small segments (waves 0-2) =======================
  // DO_SEG: MFMA chunks from the small LDS area; rows beyond M clamp to base
  // (garbage x valid W is never written); k-tails hit zero-padded W.
  #define DO_SEG(CBASE, NCH, SBOFF, STRIDE, M, NOUTS, OOFF) do {               \
    f32x4 sacc = {0.f, 0.f, 0.f, 0.f};                                         \
    _Pragma("unroll")                                                          \
    for (int c = 0; c < (NCH); ++c) {                                          \
      const uint32_t ab = 9728u + (SBOFF) +                                    \
                          ((rl < (M)) ? (uint32_t)(rl * (STRIDE)) : 0u);       \
      const float* ap = shm + ab + (uint32_t)(c * 32 + kg * 8);                \
      f32x4 lo = *(const f32x4*)ap;                                            \
      f32x4 hi = *(const f32x4*)(ap + 4);                                      \
      short8 aa = mk_frag(lo, hi);                                             \
      short8 wf = *(const short8*)(wpack2 +                                    \
                    (uint32_t)(((CBASE) + c) * 512 + kg * 64 + rl * 4));       \
      sacc = __builtin_amdgcn_mfma_f32_16x16x32_bf16(aa, wf, sacc, 0, 0, 0);   \
    }                                                                          \
    _Pragma("unroll")                                                          \
    for (int q = 0; q < 4; ++q) {                                              \
      const int rowq = kg * 4 + q;                                             \
      if (rowq < (M) && rl < (NOUTS))                                          \
        out[ob0 + (OOFF) + (uint32_t)(rowq * (NOUTS) + rl)] = sacc[q];         \
    }                                                                          \
  } while (0)

  if (wv == 0) {
    DO_SEG(24, 3, 12u,  0, 1, 16, 4u);    // status
    DO_SEG(27, 2, 112u, 0, 1, 8,  438u);  // potions
    DO_SEG(29, 1, 0u,   0, 1, 4,  0u);    // player
    DO_SEG(30, 1, 100u, 0, 1, 2,  20u);   // pinfo
  } else if (wv == 1) {
    DO_SEG(31, 4, 336u, 104, 5, 16, 462u);// monster
  } else if (wv == 2) {
    DO_SEG(35, 6, 156u, 0, 1, 16, 446u);  // relics
  }
  #undef DO_SEG
}

extern "C" void kernel_launch(void* const* d_in, const int* in_sizes, int n_in,
                              void* d_out, int out_size, void* d_ws, size_t ws_size,
                              hipStream_t stream) {
  const float* battle   = (const float*)d_in[0];
  const float* Wplayer  = (const float*)d_in[1];
  const float* Wstatus  = (const float*)d_in[2];
  const float* Wpinfo   = (const float*)d_in[3];
  const float* Wcard    = (const float*)d_in[4];
  const float* Wpotions = (const float*)d_in[5];
  const float* Wrelics  = (const float*)d_in[6];
  const float* Wmonster = (const float*)d_in[7];
  float* out = (float*)d_out;

  uint32_t* wpack2 = (uint32_t*)d_ws;    // 41*512 dwords = 84 KB packed W

  hipLaunchKernelGGL(pack_w, dim3(82), dim3(256), 0, stream,
                     Wplayer, Wstatus, Wpinfo, Wcard, Wpotions, Wrelics,
                     Wmonster, wpack2);
  hipLaunchKernelGGL(seg_gemm, dim3(32768), dim3(256), 0, stream,
                     battle, (const uint32_t*)wpack2, out);
}